// Round 8
// baseline (1538.922 us; speedup 1.0000x reference)
//
#include <hip/hip_runtime.h>
#include <cstdint>
#include <cstddef>

#define NN 50000
#define NE 800000
#define NP 50048      // 391*128 padded rows
#define ROWT 391
#define NBLK 196      // ceil((NN+1)/256)

typedef unsigned short u16;
typedef _Float16 f16;
typedef _Float16 hf8 __attribute__((ext_vector_type(8)));
typedef float f32x4 __attribute__((ext_vector_type(4)));

union U32 { unsigned u; f16 h[2]; };
union U64 { uint2 v; f16 h[4]; };
union U128 { uint4 v; f16 x[8]; };

__device__ __forceinline__ float b2f(u16 v){ return __uint_as_float((unsigned)v << 16); }
__device__ __forceinline__ u16 f2b(float f){
  unsigned u = __float_as_uint(f);
  return (u16)((u + 0x7fffu + ((u >> 16) & 1u)) >> 16);
}
// dtype-agnostic load of float input i (flag: 1 = float32, 0 = bf16)
__device__ __forceinline__ float ldf(const void* p, long i, int f32){
  return f32 ? ((const float*)p)[i] : b2f(((const u16*)p)[i]);
}
__device__ __forceinline__ void gl_lds16(const void* g, void* l){
  __builtin_amdgcn_global_load_lds((const __attribute__((address_space(1))) void*)g,
                                   (__attribute__((address_space(3))) void*)l, 16, 0, 0);
}

// ---------------- dtype detect ----------------
__global__ void detect_k(const u16* __restrict__ nf, int* __restrict__ flag)
{
  int mx = 0;
  for (int i = 0; i < 256; ++i) { int e = (nf[i] >> 7) & 0xFF; mx = e > mx ? e : mx; }
  flag[0] = (mx >= 0x90) ? 1 : 0;
}

__global__ void zero_i_k(int* __restrict__ p, int n)
{
  int i = blockIdx.x * 256 + threadIdx.x;
  if (i < n) p[i] = 0;
}

// ---------------- small-param f32 conversion table ----------------
// layout (floats): eW1[6*48]@0, eb1[6*16]@288, eb2[6*128]@384, lng[6*128]@1152,
// lnb[6*128]@1920, fb1[6*512]@2688, fb2[6*128]@5760, embB[128]@6528, embW[2560]@6656 ; total 9216
__global__ void conv_k(const void* eW1, const void* eb1, const void* eb2,
                       const void* lng, const void* lnb, const void* fb1, const void* fb2,
                       const void* embB, const void* embW,
                       float* __restrict__ pf, const int* __restrict__ dflag)
{
  int f32 = dflag[0];
  int i = blockIdx.x * 256 + threadIdx.x;
  if (i >= 9216) return;
  const void* p; long off;
  if (i < 288)       { p = eW1;  off = i; }
  else if (i < 384)  { p = eb1;  off = i - 288; }
  else if (i < 1152) { p = eb2;  off = i - 384; }
  else if (i < 1920) { p = lng;  off = i - 1152; }
  else if (i < 2688) { p = lnb;  off = i - 1920; }
  else if (i < 5760) { p = fb1;  off = i - 2688; }
  else if (i < 6528) { p = fb2;  off = i - 5760; }
  else if (i < 6656) { p = embB; off = i - 6528; }
  else               { p = embW; off = i - 6656; }
  pf[i] = ldf(p, off, f32);
}

// ---------------- weight prep ----------------
__global__ void prep_qkve_k(const void* __restrict__ Wq, const void* __restrict__ Wk,
                            const void* __restrict__ Wv, const void* __restrict__ eW2,
                            f16* __restrict__ Wcat, const int* __restrict__ dflag)
{
  int f32 = dflag[0];
  int idx = blockIdx.x * 256 + threadIdx.x;   // [6][512][128]
  int l = idx >> 16;
  int rem = idx & 65535;
  int r = rem >> 7;
  int kk = rem & 127;
  long base = (long)l * 16384;
  float val;
  if (r < 384) {
    const void* W = (r < 128) ? Wq : (r < 256) ? Wk : Wv;
    int n = r & 127;
    val = ldf(W, base + kk * 128 + n, f32);
  } else {
    int n = r - 384, h = n >> 4, j = n & 15;
    long wq = base + kk * 128 + h * 16;
    long e2 = (long)l * 2048 + j * 128 + h * 16;
    float s = 0.f;
    #pragma unroll
    for (int d = 0; d < 16; ++d) s += ldf(Wq, wq + d, f32) * ldf(eW2, e2 + d, f32);
    val = s;
  }
  Wcat[idx] = (f16)val;
}

// in [6][R][C] -> out [6][C][R] f16 (B^T layout for gemm)
__global__ void transpose_k(const void* __restrict__ in, f16* __restrict__ out, int R, int C,
                            const int* __restrict__ dflag)
{
  int f32 = dflag[0];
  int idx = blockIdx.x * 256 + threadIdx.x;
  int rc = R * C;
  int l = idx / rc, rem = idx % rc;
  int r = rem / C, c = rem % C;
  out[l * rc + c * R + r] = (f16)ldf(in, idx, f32);
}

// ---------------- CSR build ----------------
__global__ void deg_count_k(const int* __restrict__ eidx, int* __restrict__ deg)
{
  int e = blockIdx.x * 256 + threadIdx.x;
  if (e < NE) atomicAdd(&deg[eidx[NE + e]], 1);
}

__global__ void scan_a(const int* __restrict__ deg, int* __restrict__ bsum)
{
  __shared__ int tmp[256];
  int t = threadIdx.x, i = blockIdx.x * 256 + t;
  int v = (i < NN) ? deg[i] : 0;
  tmp[t] = v; __syncthreads();
  for (int o = 1; o < 256; o <<= 1) {
    int u = (t >= o) ? tmp[t - o] : 0;
    __syncthreads(); tmp[t] += u; __syncthreads();
  }
  if (t == 255) bsum[blockIdx.x] = tmp[255];
}

__global__ void scan_b(const int* __restrict__ bsum, int* __restrict__ boff) // 1 block x 256
{
  __shared__ int tmp[256];
  int t = threadIdx.x;
  int v = (t < NBLK) ? bsum[t] : 0;
  tmp[t] = v; __syncthreads();
  for (int o = 1; o < 256; o <<= 1) {
    int u = (t >= o) ? tmp[t - o] : 0;
    __syncthreads(); tmp[t] += u; __syncthreads();
  }
  if (t < NBLK) boff[t] = tmp[t] - v;  // exclusive
}

__global__ void scan_c(const int* __restrict__ deg, const int* __restrict__ boff,
                       int* __restrict__ rstart, int* __restrict__ cursor)
{
  __shared__ int tmp[256];
  int t = threadIdx.x, i = blockIdx.x * 256 + t;
  int v = (i < NN) ? deg[i] : 0;
  tmp[t] = v; __syncthreads();
  for (int o = 1; o < 256; o <<= 1) {
    int u = (t >= o) ? tmp[t - o] : 0;
    __syncthreads(); tmp[t] += u; __syncthreads();
  }
  if (i <= NN) {
    int ex = boff[blockIdx.x] + tmp[t] - v;
    rstart[i] = ex;
    if (i < NN) cursor[i] = ex;
  }
}

__global__ void csr_fill_k(const int* __restrict__ eidx, int* __restrict__ cursor,
                           int* __restrict__ csrc, int* __restrict__ ceid)
{
  int e = blockIdx.x * 256 + threadIdx.x;
  if (e >= NE) return;
  int d = eidx[NE + e];
  int slot = atomicAdd(&cursor[d], 1);
  csrc[slot] = eidx[e];
  ceid[slot] = e;
}

// gather edge attrs into CSR slot order, 4 f16 per slot (8B aligned)
__global__ void ea_gather_k(const void* __restrict__ eatt, const int* __restrict__ ceid,
                            f16* __restrict__ ea4, const int* __restrict__ dflag)
{
  int f32 = dflag[0];
  int e = blockIdx.x * 256 + threadIdx.x;
  if (e >= NE) return;
  long id = ceid[e];
  f16* q = ea4 + (size_t)e * 4;
  q[0] = (f16)ldf(eatt, id * 3 + 0, f32);
  q[1] = (f16)ldf(eatt, id * 3 + 1, f32);
  q[2] = (f16)ldf(eatt, id * 3 + 2, f32);
  q[3] = (f16)0.f;
}

// ---------------- embedding (covers padded rows with zeros) ----------------
__global__ void emb_k(const void* __restrict__ nf, const float* __restrict__ embWf,
                      const float* __restrict__ embBf, float* __restrict__ xf,
                      f16* __restrict__ xh, const int* __restrict__ dflag)
{
  int f32 = dflag[0];
  int idx = blockIdx.x * 256 + threadIdx.x;   // NP*128 exact
  int node = idx >> 7, c = idx & 127;
  float s = 0.f;
  if (node < NN) {
    s = embBf[c];
    long row = (long)node * 20;
    #pragma unroll
    for (int f = 0; f < 20; ++f) s += ldf(nf, row + f, f32) * embWf[f * 128 + c];
  }
  xf[idx] = s;
  xh[idx] = (f16)s;
}

// ---------------- MFMA GEMM: C = A[M,K] @ B (Bt[N,K]), 128x128 tile, BK=128 ----------------
// Full-K LDS staging: 16 global_load_lds issues, ONE barrier, 64 MFMAs per K-slice.
// Swapped-operand MFMA + LDS-transpose epilogue -> coalesced uint4 stores.
// MODE 0: q -> o0 (ld128), k -> o1 cols 0-127 of ld256, v -> o1 cols 128-255, qe -> o3. grid (391,4)
// MODE 1: f16 out (hb), ld 512, bias + relu. grid (391,4)
// MODE 2: bias + residual + LN2 fused; writes xf (f32) + xh (f16). grid (391,1)
template<int MODE>
__global__ __launch_bounds__(256)
void gemm_k(const f16* __restrict__ A, const f16* __restrict__ Bt, int K,
            f16* __restrict__ o0, f16* __restrict__ o1, f16* __restrict__ o3,
            const float* __restrict__ bias,
            const float* __restrict__ gf, const float* __restrict__ bpf,
            float* __restrict__ xf, f16* __restrict__ xh)
{
  __shared__ __align__(16) f16 sh[128 * 256];   // 64KB: A(128x128) + B(128x128); reused for C-tile
  f16* lA = sh;
  f16* lB = sh + 16384;
  const int tid = threadIdx.x;
  const int wave = tid >> 6, lane = tid & 63;
  const int wr = wave >> 1, wc = wave & 1;
  const size_t rowBase = (size_t)blockIdx.x * 128;
  const size_t colBase = (size_t)blockIdx.y * 128;
  const int m = lane & 15, q4 = lane >> 4;

  f32x4 zero = {0.f, 0.f, 0.f, 0.f};
  f32x4 acc[4][4];
  #pragma unroll
  for (int i = 0; i < 4; ++i)
    #pragma unroll
    for (int j = 0; j < 4; ++j) acc[i][j] = zero;

  // staging: wave stages rows [wave*32, +32) of the current 128-wide K slice.
  // issue i covers 4 rows: lane -> row = 4i + (lane>>4), 16B chunk = lane&15;
  // LDS dest = wave-base + i*1KB + lane*16B == row-major (row*256B + chunk*16B).
  const int sr4 = lane >> 4, sc16 = lane & 15;
  const f16* Ap = A + (rowBase + wave * 32 + sr4) * (size_t)K + sc16 * 8;
  const f16* Bp = Bt + (colBase + wave * 32 + sr4) * (size_t)K + sc16 * 8;
  f16* lAp = lA + wave * 4096;
  f16* lBp = lB + wave * 4096;

  for (int k0 = 0; k0 < K; k0 += 128) {
    #pragma unroll
    for (int i = 0; i < 8; ++i) {
      gl_lds16(Ap + k0 + (size_t)(4 * i) * K, lAp + i * 512);
      gl_lds16(Bp + k0 + (size_t)(4 * i) * K, lBp + i * 512);
    }
    __syncthreads();
    #pragma unroll
    for (int kk = 0; kk < 4; ++kk) {
      hf8 af[4], bf[4];
      #pragma unroll
      for (int i = 0; i < 4; ++i) {
        af[i] = *(const hf8*)(lA + (wr * 64 + i * 16 + m) * 128 + kk * 32 + q4 * 8);
        bf[i] = *(const hf8*)(lB + (wc * 64 + i * 16 + m) * 128 + kk * 32 + q4 * 8);
      }
      // swapped operands: lane holds C row (i*16+m), 4 consecutive cols per reg
      #pragma unroll
      for (int i = 0; i < 4; ++i)
        #pragma unroll
        for (int j = 0; j < 4; ++j)
          acc[i][j] = __builtin_amdgcn_mfma_f32_16x16x32_f16(bf[j], af[i], acc[i][j], 0, 0, 0);
    }
    __syncthreads();   // waves done reading before restage / C-tile overwrite
  }

  // stage C tile into LDS (stride 136 f16 keeps 16B row alignment), 8B packs
  #pragma unroll
  for (int i = 0; i < 4; ++i) {
    int crow = wr * 64 + i * 16 + m;
    #pragma unroll
    for (int j = 0; j < 4; ++j) {
      int ccol = wc * 64 + j * 16 + q4 * 4;
      float v[4];
      #pragma unroll
      for (int r = 0; r < 4; ++r) v[r] = acc[i][j][r];
      if (MODE == 1) {
        float4 bv = *(const float4*)(bias + (int)colBase + ccol);
        v[0] = fmaxf(v[0] + bv.x, 0.f); v[1] = fmaxf(v[1] + bv.y, 0.f);
        v[2] = fmaxf(v[2] + bv.z, 0.f); v[3] = fmaxf(v[3] + bv.w, 0.f);
      } else if (MODE == 2) {
        float4 bv = *(const float4*)(bias + ccol);
        v[0] += bv.x; v[1] += bv.y; v[2] += bv.z; v[3] += bv.w;
      }
      U64 pk;
      #pragma unroll
      for (int r = 0; r < 4; ++r) pk.h[r] = (f16)v[r];
      *(uint2*)(sh + crow * 136 + ccol) = pk.v;
    }
  }
  __syncthreads();

  if (MODE != 2) {
    // coalesced readout: thread -> (row = tid>>1, half = tid&1), 8 uint4 stores
    f16* o; size_t ld; int off;
    if (MODE == 0) {
      if (blockIdx.y == 0)      { o = o0; ld = 128; off = 0; }
      else if (blockIdx.y == 1) { o = o1; ld = 256; off = 0; }
      else if (blockIdx.y == 2) { o = o1; ld = 256; off = 128; }
      else                      { o = o3; ld = 128; off = 0; }
    } else { o = o0; ld = 512; off = (int)colBase; }
    int row = tid >> 1, half = tid & 1;
    const f16* srcp = sh + row * 136 + half * 64;
    f16* dstp = o + (rowBase + row) * ld + off + half * 64;
    #pragma unroll
    for (int k = 0; k < 8; ++k)
      *(uint4*)(dstp + k * 8) = *(const uint4*)(srcp + k * 8);
  } else {
    // MODE 2: fused residual + LN2. 2 threads per row; pair-reduce via shfl_xor(1).
    int row = tid >> 1, half = tid & 1;
    size_t nb = (rowBase + row) * (size_t)128 + half * 64;
    const f16* srcp = sh + row * 136 + half * 64;
    float y[64];
    float s1 = 0.f, s2 = 0.f;
    #pragma unroll
    for (int k = 0; k < 8; ++k) {
      U128 u; u.v = *(const uint4*)(srcp + k * 8);
      float4 xa = *(const float4*)(xf + nb + k * 8);
      float4 xb = *(const float4*)(xf + nb + k * 8 + 4);
      float xr[8] = { xa.x, xa.y, xa.z, xa.w, xb.x, xb.y, xb.z, xb.w };
      #pragma unroll
      for (int d = 0; d < 8; ++d) {
        float t = (float)u.x[d] + xr[d];
        y[k * 8 + d] = t; s1 += t; s2 += t * t;
      }
    }
    s1 += __shfl_xor(s1, 1); s2 += __shfl_xor(s2, 1);
    float mu = s1 * 0.0078125f;
    float var = s2 * 0.0078125f - mu * mu;
    float rstd = rsqrtf(var + 1e-5f);
    int cb = half * 64;
    #pragma unroll
    for (int k = 0; k < 8; ++k) {
      float4 oa, ob; U128 pk;
      #pragma unroll
      for (int d = 0; d < 4; ++d) {
        float ov = (y[k * 8 + d] - mu) * rstd * gf[cb + k * 8 + d] + bpf[cb + k * 8 + d];
        (&oa.x)[d] = ov; pk.x[d] = (f16)ov;
      }
      #pragma unroll
      for (int d = 0; d < 4; ++d) {
        float ov = (y[k * 8 + 4 + d] - mu) * rstd * gf[cb + k * 8 + 4 + d] + bpf[cb + k * 8 + 4 + d];
        (&ob.x)[d] = ov; pk.x[4 + d] = (f16)ov;
      }
      *(float4*)(xf + nb + k * 8) = oa;
      *(float4*)(xf + nb + k * 8 + 4) = ob;
      *(uint4*)(xh + nb + k * 8) = pk.v;
    }
  }
}

// ---------------- fused edge attention + aggregation + residual + LN1 ----------------
// One wave per node; 4 edge slots (16 lanes each, 8 channels/lane).
__global__ void fuse_k(const f16* __restrict__ qf, const f16* __restrict__ qef,
                       const f16* __restrict__ kv, const f16* __restrict__ ea4,
                       const int* __restrict__ rstart, const int* __restrict__ csrc,
                       const float* __restrict__ eW1f, const float* __restrict__ eb1f,
                       const float* __restrict__ eb2f,
                       const float* __restrict__ gf, const float* __restrict__ bpf,
                       float* __restrict__ xf, f16* __restrict__ xh)
{
  int wave = threadIdx.x >> 6, lane = threadIdx.x & 63;
  int node = blockIdx.x * 4 + wave;
  if (node >= NN) return;
  int sub = lane >> 4, l = lane & 15;
  int c0 = l << 3;
  int half = l & 1;
  size_t nb = (size_t)node * 128 + c0;

  float q[8], z[8];
  { U128 u; u.v = *(const uint4*)(qf + nb);
    #pragma unroll
    for (int i = 0; i < 8; ++i) q[i] = (float)u.x[i];
    u.v = *(const uint4*)(qef + nb);
    #pragma unroll
    for (int i = 0; i < 8; ++i) z[i] = (float)u.x[i]; }

  float pb = 0.f;
  #pragma unroll
  for (int i = 0; i < 8; ++i) pb = fmaf(q[i], eb2f[c0 + i], pb);
  pb += __shfl_xor(pb, 1);

  int j0 = half << 3;
  float w0[8], w1[8], w2[8], bb[8];
  #pragma unroll
  for (int i = 0; i < 8; ++i) {
    w0[i] = eW1f[j0 + i];
    w1[i] = eW1f[16 + j0 + i];
    w2[i] = eW1f[32 + j0 + i];
    bb[i] = eb1f[j0 + i];
  }

  float acc[8] = {0.f, 0.f, 0.f, 0.f, 0.f, 0.f, 0.f, 0.f};
  int e0 = rstart[node], e1 = rstart[node + 1];
  int e = e0 + sub;
  uint4 kN = {0,0,0,0}, vN = {0,0,0,0};
  uint2 eaN = {0,0};
  if (e < e1) {
    int s = csrc[e];
    const f16* kb = kv + (size_t)s * 256 + c0;
    kN = *(const uint4*)kb;
    vN = *(const uint4*)(kb + 128);
    eaN = *(const uint2*)(ea4 + (size_t)e * 4);
  }
  for (; e < e1; e += 4) {
    uint4 kC = kN, vC = vN; uint2 eaC = eaN;
    int en = e + 4;
    if (en < e1) {
      int s = csrc[en];
      const f16* kb = kv + (size_t)s * 256 + c0;
      kN = *(const uint4*)kb;
      vN = *(const uint4*)(kb + 128);
      eaN = *(const uint2*)(ea4 + (size_t)en * 4);
    }
    U64 ue; ue.v = eaC;
    float a0 = (float)ue.h[0], a1 = (float)ue.h[1], a2 = (float)ue.h[2];
    U128 K; K.v = kC;
    float p = 0.f;
    #pragma unroll
    for (int i = 0; i < 8; ++i) {
      float h = fmaxf(fmaf(a2, w2[i], fmaf(a1, w1[i], fmaf(a0, w0[i], bb[i]))), 0.f);
      p = fmaf(q[i], (float)K.x[i], fmaf(z[i], h, p));
    }
    p += __shfl_xor(p, 1);
    float logit = (p + pb) * 0.25f;
    float mx = logit;
    mx = fmaxf(mx, __shfl_xor(mx, 2));
    mx = fmaxf(mx, __shfl_xor(mx, 4));
    mx = fmaxf(mx, __shfl_xor(mx, 8));
    float ex = __expf(logit - mx);
    float se = ex;
    se += __shfl_xor(se, 2); se += __shfl_xor(se, 4); se += __shfl_xor(se, 8);
    float w = ex / se;
    U128 V; V.v = vC;
    #pragma unroll
    for (int i = 0; i < 8; ++i) acc[i] = fmaf(w, (float)V.x[i], acc[i]);
  }

  #pragma unroll
  for (int i = 0; i < 8; ++i) {
    acc[i] += __shfl_xor(acc[i], 16);
    acc[i] += __shfl_xor(acc[i], 32);
  }
  float4 x0 = *(const float4*)(xf + nb);
  float4 x1 = *(const float4*)(xf + nb + 4);
  float y[8] = { x0.x + acc[0], x0.y + acc[1], x0.z + acc[2], x0.w + acc[3],
                 x1.x + acc[4], x1.y + acc[5], x1.z + acc[6], x1.w + acc[7] };
  float s1 = 0.f, s2 = 0.f;
  #pragma unroll
  for (int i = 0; i < 8; ++i) { s1 += y[i]; s2 += y[i] * y[i]; }
  #pragma unroll
  for (int o = 1; o < 16; o <<= 1) { s1 += __shfl_xor(s1, o); s2 += __shfl_xor(s2, o); }
  float mu = s1 * 0.0078125f;
  float var = s2 * 0.0078125f - mu * mu;
  float rstd = rsqrtf(var + 1e-5f);
  float ov[8];
  #pragma unroll
  for (int i = 0; i < 8; ++i) ov[i] = (y[i] - mu) * rstd * gf[c0 + i] + bpf[c0 + i];
  if (sub == 0) {
    float4 s0 = { ov[0], ov[1], ov[2], ov[3] };
    float4 s1v = { ov[4], ov[5], ov[6], ov[7] };
    *(float4*)(xf + nb) = s0;
    *(float4*)(xf + nb + 4) = s1v;
    U128 wz;
    #pragma unroll
    for (int i = 0; i < 8; ++i) wz.x[i] = (f16)ov[i];
    *(uint4*)(xh + nb) = wz.v;
  }
}

__global__ void out_k(const float* __restrict__ xf, void* __restrict__ out,
                      const int* __restrict__ dflag)
{
  int f32 = dflag[0];
  int idx = blockIdx.x * 256 + threadIdx.x;   // NN*128 exact
  if (f32) ((float*)out)[idx] = xf[idx];
  else     ((u16*)out)[idx] = f2b(xf[idx]);
}

// ---------------- launch ----------------
extern "C" void kernel_launch(void* const* d_in, const int* in_sizes, int n_in,
                              void* d_out, int out_size, void* d_ws, size_t ws_size,
                              hipStream_t stream)
{
  const void* nf   = d_in[0];
  const void* eatt = d_in[1];
  const int*  eidx = (const int*)d_in[2];
  const void* embW = d_in[3];
  const void* embB = d_in[4];
  const void* Wq   = d_in[5];
  const void* Wk   = d_in[6];
  const void* Wv   = d_in[7];
  const void* eW1  = d_in[8];
  const void* eb1  = d_in[9];
  const void* eW2  = d_in[10];
  const void* eb2  = d_in[11];
  const void* lng  = d_in[12];
  const void* lnb  = d_in[13];
  const void* fW1  = d_in[14];
  const void* fb1  = d_in[15];
  const void* fW2  = d_in[16];
  const void* fb2  = d_in[17];

  char* p = (char*)d_ws;
  auto alloc = [&](size_t b) { char* r = p; p += (b + 255) & ~(size_t)255; return r; };
  int* dflag   = (int*)alloc(256);
  float* pf    = (float*)alloc(9216 * 4);
  float* xf    = (float*)alloc((size_t)NP * 128 * 4);
  f16*   xh    = (f16*)  alloc((size_t)NP * 128 * 2);
  int* deg     = (int*)alloc((NN + 1) * 4);
  int* rst     = (int*)alloc((NN + 1) * 4);
  int* cur     = (int*)alloc((size_t)NN * 4);
  int* bsum    = (int*)alloc(NBLK * 4);
  int* boff    = (int*)alloc(NBLK * 4);
  int* csrc    = (int*)alloc((size_t)NE * 4);
  f16* ea4     = (f16*)alloc((size_t)NE * 4 * 2);
  f16* Wcat    = (f16*)alloc((size_t)6 * 512 * 128 * 2);
  f16* W1t     = (f16*)alloc((size_t)6 * 512 * 128 * 2);
  f16* W2t     = (f16*)alloc((size_t)6 * 128 * 512 * 2);
  // layer scratch S: edge phase = qf + qe + kv; ff phase = hb
  char* S    = alloc((size_t)NP * 512 * 2 + (size_t)NP * 128 * 2);
  f16* qf  = (f16*)S;
  f16* qe  = qf + (size_t)NP * 128;
  f16* kv  = qe + (size_t)NP * 128;   // [node][256]: k cols 0-127, v cols 128-255
  f16* hb  = (f16*)S;
  int* ceid = (int*)S;                 // build phase only

  float* eW1f = pf;          // +l*48
  float* eb1f = pf + 288;    // +l*16
  float* eb2f = pf + 384;    // +l*128
  float* lngf = pf + 1152;   // +l*128
  float* lnbf = pf + 1920;   // +l*128
  float* fb1f = pf + 2688;   // +l*512
  float* fb2f = pf + 5760;   // +l*128
  float* embBf = pf + 6528;
  float* embWf = pf + 6656;

  detect_k<<<1, 1, 0, stream>>>((const u16*)nf, dflag);
  conv_k<<<36, 256, 0, stream>>>(eW1, eb1, eb2, lng, lnb, fb1, fb2, embB, embW, pf, dflag);
  prep_qkve_k<<<1536, 256, 0, stream>>>(Wq, Wk, Wv, eW2, Wcat, dflag);
  transpose_k<<<1536, 256, 0, stream>>>(fW1, W1t, 128, 512, dflag);
  transpose_k<<<1536, 256, 0, stream>>>(fW2, W2t, 512, 128, dflag);
  zero_i_k<<<(NN + 256) / 256, 256, 0, stream>>>(deg, NN + 1);
  deg_count_k<<<3125, 256, 0, stream>>>(eidx, deg);
  scan_a<<<NBLK, 256, 0, stream>>>(deg, bsum);
  scan_b<<<1, 256, 0, stream>>>(bsum, boff);
  scan_c<<<NBLK, 256, 0, stream>>>(deg, boff, rst, cur);
  csr_fill_k<<<3125, 256, 0, stream>>>(eidx, cur, csrc, ceid);
  ea_gather_k<<<3125, 256, 0, stream>>>(eatt, ceid, ea4, dflag);
  emb_k<<<NP * 128 / 256, 256, 0, stream>>>(nf, embWf, embBf, xf, xh, dflag);

  for (int l = 0; l < 6; ++l) {
    gemm_k<0><<<dim3(ROWT, 4), 256, 0, stream>>>(xh, Wcat + (size_t)l * 65536, 128,
                                                 qf, kv, qe, nullptr,
                                                 nullptr, nullptr, nullptr, nullptr);
    fuse_k<<<12500, 256, 0, stream>>>(qf, qe, kv, ea4, rst, csrc,
                                      eW1f + l * 48, eb1f + l * 16, eb2f + l * 128,
                                      lngf + l * 128, lnbf + l * 128, xf, xh);
    gemm_k<1><<<dim3(ROWT, 4), 256, 0, stream>>>(xh, W1t + (size_t)l * 65536, 128,
                                                 hb, nullptr, nullptr, fb1f + l * 512,
                                                 nullptr, nullptr, nullptr, nullptr);
    gemm_k<2><<<dim3(ROWT, 1), 256, 0, stream>>>(hb, W2t + (size_t)l * 65536, 512,
                                                 nullptr, nullptr, nullptr, fb2f + l * 128,
                                                 lngf + l * 128, lnbf + l * 128, xf, xh);
  }
  out_k<<<25000, 256, 0, stream>>>(xf, d_out, dflag);
}

// Round 9
// 1329.837 us; speedup vs baseline: 1.1572x; 1.1572x over previous
//
#include <hip/hip_runtime.h>
#include <cstdint>
#include <cstddef>

#define NN 50000
#define NE 800000
#define NP 50048      // 391*128 padded rows
#define ROWT 391
#define NBLK 196      // ceil((NN+1)/256)

typedef unsigned short u16;
typedef _Float16 f16;
typedef _Float16 hf8 __attribute__((ext_vector_type(8)));
typedef float f32x4 __attribute__((ext_vector_type(4)));

union U32 { unsigned u; f16 h[2]; };
union U64 { uint2 v; f16 h[4]; };
union U128 { uint4 v; f16 x[8]; };

__device__ __forceinline__ float b2f(u16 v){ return __uint_as_float((unsigned)v << 16); }
__device__ __forceinline__ u16 f2b(float f){
  unsigned u = __float_as_uint(f);
  return (u16)((u + 0x7fffu + ((u >> 16) & 1u)) >> 16);
}
// dtype-agnostic load of float input i (flag: 1 = float32, 0 = bf16)
__device__ __forceinline__ float ldf(const void* p, long i, int f32){
  return f32 ? ((const float*)p)[i] : b2f(((const u16*)p)[i]);
}
__device__ __forceinline__ void gl_lds16(const void* g, void* l){
  __builtin_amdgcn_global_load_lds((const __attribute__((address_space(1))) void*)g,
                                   (__attribute__((address_space(3))) void*)l, 16, 0, 0);
}

// ---------------- dtype detect ----------------
__global__ void detect_k(const u16* __restrict__ nf, int* __restrict__ flag)
{
  int mx = 0;
  for (int i = 0; i < 256; ++i) { int e = (nf[i] >> 7) & 0xFF; mx = e > mx ? e : mx; }
  flag[0] = (mx >= 0x90) ? 1 : 0;
}

__global__ void zero_i_k(int* __restrict__ p, int n)
{
  int i = blockIdx.x * 256 + threadIdx.x;
  if (i < n) p[i] = 0;
}

// ---------------- small-param f32 conversion table ----------------
// layout (floats): eW1[6*48]@0, eb1[6*16]@288, eb2[6*128]@384, lng[6*128]@1152,
// lnb[6*128]@1920, fb1[6*512]@2688, fb2[6*128]@5760, embB[128]@6528, embW[2560]@6656 ; total 9216
__global__ void conv_k(const void* eW1, const void* eb1, const void* eb2,
                       const void* lng, const void* lnb, const void* fb1, const void* fb2,
                       const void* embB, const void* embW,
                       float* __restrict__ pf, const int* __restrict__ dflag)
{
  int f32 = dflag[0];
  int i = blockIdx.x * 256 + threadIdx.x;
  if (i >= 9216) return;
  const void* p; long off;
  if (i < 288)       { p = eW1;  off = i; }
  else if (i < 384)  { p = eb1;  off = i - 288; }
  else if (i < 1152) { p = eb2;  off = i - 384; }
  else if (i < 1920) { p = lng;  off = i - 1152; }
  else if (i < 2688) { p = lnb;  off = i - 1920; }
  else if (i < 5760) { p = fb1;  off = i - 2688; }
  else if (i < 6528) { p = fb2;  off = i - 5760; }
  else if (i < 6656) { p = embB; off = i - 6528; }
  else               { p = embW; off = i - 6656; }
  pf[i] = ldf(p, off, f32);
}

// ---------------- weight prep ----------------
__global__ void prep_qkve_k(const void* __restrict__ Wq, const void* __restrict__ Wk,
                            const void* __restrict__ Wv, const void* __restrict__ eW2,
                            f16* __restrict__ Wcat, const int* __restrict__ dflag)
{
  int f32 = dflag[0];
  int idx = blockIdx.x * 256 + threadIdx.x;   // [6][512][128]
  int l = idx >> 16;
  int rem = idx & 65535;
  int r = rem >> 7;
  int kk = rem & 127;
  long base = (long)l * 16384;
  float val;
  if (r < 384) {
    const void* W = (r < 128) ? Wq : (r < 256) ? Wk : Wv;
    int n = r & 127;
    val = ldf(W, base + kk * 128 + n, f32);
  } else {
    int n = r - 384, h = n >> 4, j = n & 15;
    long wq = base + kk * 128 + h * 16;
    long e2 = (long)l * 2048 + j * 128 + h * 16;
    float s = 0.f;
    #pragma unroll
    for (int d = 0; d < 16; ++d) s += ldf(Wq, wq + d, f32) * ldf(eW2, e2 + d, f32);
    val = s;
  }
  Wcat[idx] = (f16)val;
}

// in [6][R][C] -> out [6][C][R] f16 (B^T layout for gemm)
__global__ void transpose_k(const void* __restrict__ in, f16* __restrict__ out, int R, int C,
                            const int* __restrict__ dflag)
{
  int f32 = dflag[0];
  int idx = blockIdx.x * 256 + threadIdx.x;
  int rc = R * C;
  int l = idx / rc, rem = idx % rc;
  int r = rem / C, c = rem % C;
  out[l * rc + c * R + r] = (f16)ldf(in, idx, f32);
}

// ---------------- CSR build ----------------
__global__ void deg_count_k(const int* __restrict__ eidx, int* __restrict__ deg)
{
  int e = blockIdx.x * 256 + threadIdx.x;
  if (e < NE) atomicAdd(&deg[eidx[NE + e]], 1);
}

__global__ void scan_a(const int* __restrict__ deg, int* __restrict__ bsum)
{
  __shared__ int tmp[256];
  int t = threadIdx.x, i = blockIdx.x * 256 + t;
  int v = (i < NN) ? deg[i] : 0;
  tmp[t] = v; __syncthreads();
  for (int o = 1; o < 256; o <<= 1) {
    int u = (t >= o) ? tmp[t - o] : 0;
    __syncthreads(); tmp[t] += u; __syncthreads();
  }
  if (t == 255) bsum[blockIdx.x] = tmp[255];
}

__global__ void scan_b(const int* __restrict__ bsum, int* __restrict__ boff) // 1 block x 256
{
  __shared__ int tmp[256];
  int t = threadIdx.x;
  int v = (t < NBLK) ? bsum[t] : 0;
  tmp[t] = v; __syncthreads();
  for (int o = 1; o < 256; o <<= 1) {
    int u = (t >= o) ? tmp[t - o] : 0;
    __syncthreads(); tmp[t] += u; __syncthreads();
  }
  if (t < NBLK) boff[t] = tmp[t] - v;  // exclusive
}

__global__ void scan_c(const int* __restrict__ deg, const int* __restrict__ boff,
                       int* __restrict__ rstart, int* __restrict__ cursor)
{
  __shared__ int tmp[256];
  int t = threadIdx.x, i = blockIdx.x * 256 + t;
  int v = (i < NN) ? deg[i] : 0;
  tmp[t] = v; __syncthreads();
  for (int o = 1; o < 256; o <<= 1) {
    int u = (t >= o) ? tmp[t - o] : 0;
    __syncthreads(); tmp[t] += u; __syncthreads();
  }
  if (i <= NN) {
    int ex = boff[blockIdx.x] + tmp[t] - v;
    rstart[i] = ex;
    if (i < NN) cursor[i] = ex;
  }
}

__global__ void csr_fill_k(const int* __restrict__ eidx, int* __restrict__ cursor,
                           int* __restrict__ csrc, int* __restrict__ ceid)
{
  int e = blockIdx.x * 256 + threadIdx.x;
  if (e >= NE) return;
  int d = eidx[NE + e];
  int slot = atomicAdd(&cursor[d], 1);
  csrc[slot] = eidx[e];
  ceid[slot] = e;
}

// gather edge attrs into CSR slot order, 4 f16 per slot (8B aligned)
__global__ void ea_gather_k(const void* __restrict__ eatt, const int* __restrict__ ceid,
                            f16* __restrict__ ea4, const int* __restrict__ dflag)
{
  int f32 = dflag[0];
  int e = blockIdx.x * 256 + threadIdx.x;
  if (e >= NE) return;
  long id = ceid[e];
  f16* q = ea4 + (size_t)e * 4;
  q[0] = (f16)ldf(eatt, id * 3 + 0, f32);
  q[1] = (f16)ldf(eatt, id * 3 + 1, f32);
  q[2] = (f16)ldf(eatt, id * 3 + 2, f32);
  q[3] = (f16)0.f;
}

// ---------------- embedding (covers padded rows with zeros) ----------------
__global__ void emb_k(const void* __restrict__ nf, const float* __restrict__ embWf,
                      const float* __restrict__ embBf, float* __restrict__ xf,
                      f16* __restrict__ xh, const int* __restrict__ dflag)
{
  int f32 = dflag[0];
  int idx = blockIdx.x * 256 + threadIdx.x;   // NP*128 exact
  int node = idx >> 7, c = idx & 127;
  float s = 0.f;
  if (node < NN) {
    s = embBf[c];
    long row = (long)node * 20;
    #pragma unroll
    for (int f = 0; f < 20; ++f) s += ldf(nf, row + f, f32) * embWf[f * 128 + c];
  }
  xf[idx] = s;
  xh[idx] = (f16)s;
}

// ---------------- MFMA GEMM: C = A[M,K] @ B (Bt[N,K]), 128x128 tile, BK=64 ----------------
// (measured-best staging config: 32KB LDS, ~5 blocks/CU)
// MODE 0: direct epilogue. q -> o0 (ld128), k -> o1 cols 0-127 of ld256, v -> o1 cols 128-255,
//         qe -> o3 (ld128). grid (391,4)
// MODE 1: direct epilogue, f16 out (hb), ld 512, bias + relu. grid (391,4)
// MODE 2: swapped-operand MFMA + LDS transpose + fused bias+residual+LN2 -> xf/xh. grid (391,1)
template<int MODE>
__global__ __launch_bounds__(256)
void gemm_k(const f16* __restrict__ A, const f16* __restrict__ Bt, int K,
            f16* __restrict__ o0, f16* __restrict__ o1, f16* __restrict__ o3,
            const float* __restrict__ bias,
            const float* __restrict__ gf, const float* __restrict__ bpf,
            float* __restrict__ xf, f16* __restrict__ xh)
{
  __shared__ __align__(16) f16 sh[MODE == 2 ? 17408 : 16384]; // staging 2x8192; MODE2 C-tile 128x136
  f16* lA = sh;
  f16* lB = sh + 8192;
  const int tid = threadIdx.x;
  const int wave = tid >> 6, lane = tid & 63;
  const int wr = wave >> 1, wc = wave & 1;
  const size_t rowBase = (size_t)blockIdx.x * 128;
  const size_t colBase = (size_t)blockIdx.y * 128;
  const int m = lane & 15, q4 = lane >> 4;

  f32x4 zero = {0.f, 0.f, 0.f, 0.f};
  f32x4 acc[4][4];
  #pragma unroll
  for (int i = 0; i < 4; ++i)
    #pragma unroll
    for (int j = 0; j < 4; ++j) acc[i][j] = zero;

  const int sr = lane >> 3, sc = lane & 7;   // staging: 8 lanes per row, 16B chunks
  const f16* Ap = A + (rowBase + wave * 32 + sr) * (size_t)K + sc * 8;
  const f16* Bp = Bt + (colBase + wave * 32 + sr) * (size_t)K + sc * 8;
  f16* lAp = lA + wave * 2048;   // wave's 32 rows x 64 f16
  f16* lBp = lB + wave * 2048;

  for (int k0 = 0; k0 < K; k0 += 64) {
    #pragma unroll
    for (int i = 0; i < 4; ++i) {
      gl_lds16(Ap + k0 + (size_t)(8 * i) * K, lAp + i * 512);
      gl_lds16(Bp + k0 + (size_t)(8 * i) * K, lBp + i * 512);
    }
    __syncthreads();
    hf8 af[2][4], bf[2][4];
    #pragma unroll
    for (int s = 0; s < 2; ++s)
      #pragma unroll
      for (int i = 0; i < 4; ++i) {
        af[s][i] = *(const hf8*)(lA + (wr * 64 + i * 16 + m) * 64 + s * 32 + q4 * 8);
        bf[s][i] = *(const hf8*)(lB + (wc * 64 + i * 16 + m) * 64 + s * 32 + q4 * 8);
      }
    #pragma unroll
    for (int s = 0; s < 2; ++s)
      #pragma unroll
      for (int i = 0; i < 4; ++i)
        #pragma unroll
        for (int j = 0; j < 4; ++j) {
          if (MODE == 2)   // swapped: lane holds C row (i*16+m), 4 consecutive cols per reg
            acc[i][j] = __builtin_amdgcn_mfma_f32_16x16x32_f16(bf[s][j], af[s][i], acc[i][j], 0, 0, 0);
          else             // direct: C/D col = lane&15, row = q4*4 + reg (verified m89/m91)
            acc[i][j] = __builtin_amdgcn_mfma_f32_16x16x32_f16(af[s][i], bf[s][j], acc[i][j], 0, 0, 0);
        }
    __syncthreads();
  }

  if (MODE == 0) {
    f16* o; size_t ld; int off;
    if (blockIdx.y == 0)      { o = o0; ld = 128; off = 0; }
    else if (blockIdx.y == 1) { o = o1; ld = 256; off = 0; }
    else if (blockIdx.y == 2) { o = o1; ld = 256; off = 128; }
    else                      { o = o3; ld = 128; off = 0; }
    #pragma unroll
    for (int i = 0; i < 4; ++i)
      #pragma unroll
      for (int r = 0; r < 4; ++r) {
        size_t row = rowBase + wr * 64 + i * 16 + q4 * 4 + r;
        #pragma unroll
        for (int j = 0; j < 4; ++j) {
          int col = wc * 64 + j * 16 + m;
          o[row * ld + off + col] = (f16)acc[i][j][r];
        }
      }
  } else if (MODE == 1) {
    #pragma unroll
    for (int j = 0; j < 4; ++j) {
      int colg = (int)colBase + wc * 64 + j * 16 + m;
      float bv = bias[colg];
      #pragma unroll
      for (int i = 0; i < 4; ++i)
        #pragma unroll
        for (int r = 0; r < 4; ++r) {
          size_t row = rowBase + wr * 64 + i * 16 + q4 * 4 + r;
          o0[row * 512 + colg] = (f16)fmaxf(acc[i][j][r] + bv, 0.f);
        }
    }
  } else {
    // MODE 2: stage C tile (bias applied) into LDS, stride 136, then fused residual+LN2
    #pragma unroll
    for (int i = 0; i < 4; ++i) {
      int crow = wr * 64 + i * 16 + m;
      #pragma unroll
      for (int j = 0; j < 4; ++j) {
        int ccol = wc * 64 + j * 16 + q4 * 4;
        float4 bv = *(const float4*)(bias + ccol);
        U64 pk;
        pk.h[0] = (f16)(acc[i][j][0] + bv.x);
        pk.h[1] = (f16)(acc[i][j][1] + bv.y);
        pk.h[2] = (f16)(acc[i][j][2] + bv.z);
        pk.h[3] = (f16)(acc[i][j][3] + bv.w);
        *(uint2*)(sh + crow * 136 + ccol) = pk.v;
      }
    }
    __syncthreads();
    // 2 threads per row; pair-reduce via shfl_xor(1)
    int row = tid >> 1, half = tid & 1;
    size_t nb = (rowBase + row) * (size_t)128 + half * 64;
    const f16* srcp = sh + row * 136 + half * 64;
    float y[64];
    float s1 = 0.f, s2 = 0.f;
    #pragma unroll
    for (int k = 0; k < 8; ++k) {
      U128 u; u.v = *(const uint4*)(srcp + k * 8);
      float4 xa = *(const float4*)(xf + nb + k * 8);
      float4 xb = *(const float4*)(xf + nb + k * 8 + 4);
      float xr[8] = { xa.x, xa.y, xa.z, xa.w, xb.x, xb.y, xb.z, xb.w };
      #pragma unroll
      for (int d = 0; d < 8; ++d) {
        float t = (float)u.x[d] + xr[d];
        y[k * 8 + d] = t; s1 += t; s2 += t * t;
      }
    }
    s1 += __shfl_xor(s1, 1); s2 += __shfl_xor(s2, 1);
    float mu = s1 * 0.0078125f;
    float var = s2 * 0.0078125f - mu * mu;
    float rstd = rsqrtf(var + 1e-5f);
    int cb = half * 64;
    #pragma unroll
    for (int k = 0; k < 8; ++k) {
      float4 oa, ob; U128 pk;
      #pragma unroll
      for (int d = 0; d < 4; ++d) {
        float ov = (y[k * 8 + d] - mu) * rstd * gf[cb + k * 8 + d] + bpf[cb + k * 8 + d];
        (&oa.x)[d] = ov; pk.x[d] = (f16)ov;
      }
      #pragma unroll
      for (int d = 0; d < 4; ++d) {
        float ov = (y[k * 8 + 4 + d] - mu) * rstd * gf[cb + k * 8 + 4 + d] + bpf[cb + k * 8 + 4 + d];
        (&ob.x)[d] = ov; pk.x[4 + d] = (f16)ov;
      }
      *(float4*)(xf + nb + k * 8) = oa;
      *(float4*)(xf + nb + k * 8 + 4) = ob;
      *(uint4*)(xh + nb + k * 8) = pk.v;
    }
  }
}

// ---------------- fused edge attention + aggregation + residual + LN1 ----------------
// One wave per node; 4 edge slots (16 lanes each, 8 channels/lane).
__global__ void fuse_k(const f16* __restrict__ qf, const f16* __restrict__ qef,
                       const f16* __restrict__ kv, const f16* __restrict__ ea4,
                       const int* __restrict__ rstart, const int* __restrict__ csrc,
                       const float* __restrict__ eW1f, const float* __restrict__ eb1f,
                       const float* __restrict__ eb2f,
                       const float* __restrict__ gf, const float* __restrict__ bpf,
                       float* __restrict__ xf, f16* __restrict__ xh)
{
  int wave = threadIdx.x >> 6, lane = threadIdx.x & 63;
  int node = blockIdx.x * 4 + wave;
  if (node >= NN) return;
  int sub = lane >> 4, l = lane & 15;
  int c0 = l << 3;
  int half = l & 1;
  size_t nb = (size_t)node * 128 + c0;

  float q[8], z[8];
  { U128 u; u.v = *(const uint4*)(qf + nb);
    #pragma unroll
    for (int i = 0; i < 8; ++i) q[i] = (float)u.x[i];
    u.v = *(const uint4*)(qef + nb);
    #pragma unroll
    for (int i = 0; i < 8; ++i) z[i] = (float)u.x[i]; }

  float pb = 0.f;
  #pragma unroll
  for (int i = 0; i < 8; ++i) pb = fmaf(q[i], eb2f[c0 + i], pb);
  pb += __shfl_xor(pb, 1);

  int j0 = half << 3;
  float w0[8], w1[8], w2[8], bb[8];
  #pragma unroll
  for (int i = 0; i < 8; ++i) {
    w0[i] = eW1f[j0 + i];
    w1[i] = eW1f[16 + j0 + i];
    w2[i] = eW1f[32 + j0 + i];
    bb[i] = eb1f[j0 + i];
  }

  float acc[8] = {0.f, 0.f, 0.f, 0.f, 0.f, 0.f, 0.f, 0.f};
  int e0 = rstart[node], e1 = rstart[node + 1];
  int e = e0 + sub;
  uint4 kN = {0,0,0,0}, vN = {0,0,0,0};
  uint2 eaN = {0,0};
  if (e < e1) {
    int s = csrc[e];
    const f16* kb = kv + (size_t)s * 256 + c0;
    kN = *(const uint4*)kb;
    vN = *(const uint4*)(kb + 128);
    eaN = *(const uint2*)(ea4 + (size_t)e * 4);
  }
  for (; e < e1; e += 4) {
    uint4 kC = kN, vC = vN; uint2 eaC = eaN;
    int en = e + 4;
    if (en < e1) {
      int s = csrc[en];
      const f16* kb = kv + (size_t)s * 256 + c0;
      kN = *(const uint4*)kb;
      vN = *(const uint4*)(kb + 128);
      eaN = *(const uint2*)(ea4 + (size_t)en * 4);
    }
    U64 ue; ue.v = eaC;
    float a0 = (float)ue.h[0], a1 = (float)ue.h[1], a2 = (float)ue.h[2];
    U128 K; K.v = kC;
    float p = 0.f;
    #pragma unroll
    for (int i = 0; i < 8; ++i) {
      float h = fmaxf(fmaf(a2, w2[i], fmaf(a1, w1[i], fmaf(a0, w0[i], bb[i]))), 0.f);
      p = fmaf(q[i], (float)K.x[i], fmaf(z[i], h, p));
    }
    p += __shfl_xor(p, 1);
    float logit = (p + pb) * 0.25f;
    float mx = logit;
    mx = fmaxf(mx, __shfl_xor(mx, 2));
    mx = fmaxf(mx, __shfl_xor(mx, 4));
    mx = fmaxf(mx, __shfl_xor(mx, 8));
    float ex = __expf(logit - mx);
    float se = ex;
    se += __shfl_xor(se, 2); se += __shfl_xor(se, 4); se += __shfl_xor(se, 8);
    float w = ex / se;
    U128 V; V.v = vC;
    #pragma unroll
    for (int i = 0; i < 8; ++i) acc[i] = fmaf(w, (float)V.x[i], acc[i]);
  }

  #pragma unroll
  for (int i = 0; i < 8; ++i) {
    acc[i] += __shfl_xor(acc[i], 16);
    acc[i] += __shfl_xor(acc[i], 32);
  }
  float4 x0 = *(const float4*)(xf + nb);
  float4 x1 = *(const float4*)(xf + nb + 4);
  float y[8] = { x0.x + acc[0], x0.y + acc[1], x0.z + acc[2], x0.w + acc[3],
                 x1.x + acc[4], x1.y + acc[5], x1.z + acc[6], x1.w + acc[7] };
  float s1 = 0.f, s2 = 0.f;
  #pragma unroll
  for (int i = 0; i < 8; ++i) { s1 += y[i]; s2 += y[i] * y[i]; }
  #pragma unroll
  for (int o = 1; o < 16; o <<= 1) { s1 += __shfl_xor(s1, o); s2 += __shfl_xor(s2, o); }
  float mu = s1 * 0.0078125f;
  float var = s2 * 0.0078125f - mu * mu;
  float rstd = rsqrtf(var + 1e-5f);
  float ov[8];
  #pragma unroll
  for (int i = 0; i < 8; ++i) ov[i] = (y[i] - mu) * rstd * gf[c0 + i] + bpf[c0 + i];
  if (sub == 0) {
    float4 s0 = { ov[0], ov[1], ov[2], ov[3] };
    float4 s1v = { ov[4], ov[5], ov[6], ov[7] };
    *(float4*)(xf + nb) = s0;
    *(float4*)(xf + nb + 4) = s1v;
    U128 wz;
    #pragma unroll
    for (int i = 0; i < 8; ++i) wz.x[i] = (f16)ov[i];
    *(uint4*)(xh + nb) = wz.v;
  }
}

__global__ void out_k(const float* __restrict__ xf, void* __restrict__ out,
                      const int* __restrict__ dflag)
{
  int f32 = dflag[0];
  int idx = blockIdx.x * 256 + threadIdx.x;   // NN*128 exact
  if (f32) ((float*)out)[idx] = xf[idx];
  else     ((u16*)out)[idx] = f2b(xf[idx]);
}

// ---------------- launch ----------------
extern "C" void kernel_launch(void* const* d_in, const int* in_sizes, int n_in,
                              void* d_out, int out_size, void* d_ws, size_t ws_size,
                              hipStream_t stream)
{
  const void* nf   = d_in[0];
  const void* eatt = d_in[1];
  const int*  eidx = (const int*)d_in[2];
  const void* embW = d_in[3];
  const void* embB = d_in[4];
  const void* Wq   = d_in[5];
  const void* Wk   = d_in[6];
  const void* Wv   = d_in[7];
  const void* eW1  = d_in[8];
  const void* eb1  = d_in[9];
  const void* eW2  = d_in[10];
  const void* eb2  = d_in[11];
  const void* lng  = d_in[12];
  const void* lnb  = d_in[13];
  const void* fW1  = d_in[14];
  const void* fb1  = d_in[15];
  const void* fW2  = d_in[16];
  const void* fb2  = d_in[17];

  char* p = (char*)d_ws;
  auto alloc = [&](size_t b) { char* r = p; p += (b + 255) & ~(size_t)255; return r; };
  int* dflag   = (int*)alloc(256);
  float* pf    = (float*)alloc(9216 * 4);
  float* xf    = (float*)alloc((size_t)NP * 128 * 4);
  f16*   xh    = (f16*)  alloc((size_t)NP * 128 * 2);
  int* deg     = (int*)alloc((NN + 1) * 4);
  int* rst     = (int*)alloc((NN + 1) * 4);
  int* cur     = (int*)alloc((size_t)NN * 4);
  int* bsum    = (int*)alloc(NBLK * 4);
  int* boff    = (int*)alloc(NBLK * 4);
  int* csrc    = (int*)alloc((size_t)NE * 4);
  f16* ea4     = (f16*)alloc((size_t)NE * 4 * 2);
  f16* Wcat    = (f16*)alloc((size_t)6 * 512 * 128 * 2);
  f16* W1t     = (f16*)alloc((size_t)6 * 512 * 128 * 2);
  f16* W2t     = (f16*)alloc((size_t)6 * 128 * 512 * 2);
  // layer scratch S: edge phase = qf + qe + kv; ff phase = hb
  char* S    = alloc((size_t)NP * 512 * 2 + (size_t)NP * 128 * 2);
  f16* qf  = (f16*)S;
  f16* qe  = qf + (size_t)NP * 128;
  f16* kv  = qe + (size_t)NP * 128;   // [node][256]: k cols 0-127, v cols 128-255
  f16* hb  = (f16*)S;
  int* ceid = (int*)S;                 // build phase only

  float* eW1f = pf;          // +l*48
  float* eb1f = pf + 288;    // +l*16
  float* eb2f = pf + 384;    // +l*128
  float* lngf = pf + 1152;   // +l*128
  float* lnbf = pf + 1920;   // +l*128
  float* fb1f = pf + 2688;   // +l*512
  float* fb2f = pf + 5760;   // +l*128
  float* embBf = pf + 6528;
  float* embWf = pf + 6656;

  detect_k<<<1, 1, 0, stream>>>((const u16*)nf, dflag);
  conv_k<<<36, 256, 0, stream>>>(eW1, eb1, eb2, lng, lnb, fb1, fb2, embB, embW, pf, dflag);
  prep_qkve_k<<<1536, 256, 0, stream>>>(Wq, Wk, Wv, eW2, Wcat, dflag);
  transpose_k<<<1536, 256, 0, stream>>>(fW1, W1t, 128, 512, dflag);
  transpose_k<<<1536, 256, 0, stream>>>(fW2, W2t, 512, 128, dflag);
  zero_i_k<<<(NN + 256) / 256, 256, 0, stream>>>(deg, NN + 1);
  deg_count_k<<<3125, 256, 0, stream>>>(eidx, deg);
  scan_a<<<NBLK, 256, 0, stream>>>(deg, bsum);
  scan_b<<<1, 256, 0, stream>>>(bsum, boff);
  scan_c<<<NBLK, 256, 0, stream>>>(deg, boff, rst, cur);
  csr_fill_k<<<3125, 256, 0, stream>>>(eidx, cur, csrc, ceid);
  ea_gather_k<<<3125, 256, 0, stream>>>(eatt, ceid, ea4, dflag);
  emb_k<<<NP * 128 / 256, 256, 0, stream>>>(nf, embWf, embBf, xf, xh, dflag);

  for (int l = 0; l < 6; ++l) {
    gemm_k<0><<<dim3(ROWT, 4), 256, 0, stream>>>(xh, Wcat + (size_t)l * 65536, 128,
                                                 qf, kv, qe, nullptr,
                                                 nullptr, nullptr, nullptr, nullptr);
    fuse_k<<<12500, 256, 0, stream>>>(qf, qe, kv, ea4, rst, csrc,
                                      eW1f + l * 48, eb1f + l * 16, eb2f + l * 128,
                                      lngf + l * 128, lnbf + l * 128, xf, xh);
    gemm_k<1><<<dim3(ROWT, 4), 256, 0, stream>>>(xh, W1t + (size_t)l * 65536, 128,
                                                 hb, nullptr, nullptr, fb1f + l * 512,
                                                 nullptr, nullptr, nullptr, nullptr);
    gemm_k<2><<<dim3(ROWT, 1), 256, 0, stream>>>(hb, W2t + (size_t)l * 65536, 512,
                                                 nullptr, nullptr, nullptr, fb2f + l * 128,
                                                 lngf + l * 128, lnbf + l * 128, xf, xh);
  }
  out_k<<<25000, 256, 0, stream>>>(xf, d_out, dflag);
}